// Round 11
// baseline (1076.066 us; speedup 1.0000x reference)
//
#include <hip/hip_runtime.h>
#include <hip/hip_bf16.h>

#define NN 1024   // nodes = 32*32
#define EE 1984   // grid edges

// ---------------- edge index -> endpoints (matches grid_edges) ----------------
__device__ __forceinline__ void edge_uv(int e, int* u, int* v) {
    if (e < 992) {             // horizontal: idx[:, :-1] -> idx[:, 1:]
        int r = e / 31, c = e - r * 31;
        *u = r * 32 + c; *v = *u + 1;
    } else {                   // vertical: idx[:-1, :] -> idx[1:, :]
        *u = e - 992; *v = *u + 32;
    }
}

// ================== device-scope producer/consumer handshake =================
__device__ __forceinline__ void signal_done(int* cnt) {
    __threadfence();                       // each thread's stores visible device-wide
    __syncthreads();                       // all threads fenced before signal
    if (threadIdx.x == 0)
        __hip_atomic_fetch_add(cnt, 1, __ATOMIC_RELEASE, __HIP_MEMORY_SCOPE_AGENT);
}
__device__ __forceinline__ void wait_for(const int* cnt, int target) {
    if (threadIdx.x == 0) {
        while (__hip_atomic_load(cnt, __ATOMIC_ACQUIRE, __HIP_MEMORY_SCOPE_AGENT) < target)
            __builtin_amdgcn_s_sleep(8);
    }
    __syncthreads();
    __threadfence();                       // acquire for all threads
}

// ======================= conv 1x1 tile (1024 threads) ========================
__device__ void conv1x1_tile(const float* __restrict__ in, const float* __restrict__ in2,
                             const float* __restrict__ w,
                             float* __restrict__ out, int CIN, int Cout,
                             int b, int co0, int n0, float* red) {
    int tid = threadIdx.x;
    int px = tid & 63, kc = tid >> 6;
    int kcu = __builtin_amdgcn_readfirstlane(kc);   // wave-uniform -> s_loads for w
    int KCH = CIN >> 4;
    size_t ibase = (size_t)b * CIN * NN + n0 + px;
    const float* wr = w + (size_t)co0 * CIN;
    float acc[8] = {0.f,0.f,0.f,0.f,0.f,0.f,0.f,0.f};
    for (int ci = kcu * KCH; ci < kcu * KCH + KCH; ++ci) {
        float xv = in[ibase + (size_t)ci * NN];
        if (in2) xv += in2[ibase + (size_t)ci * NN];
#pragma unroll
        for (int j = 0; j < 8; ++j)
            acc[j] += wr[j * CIN + ci] * xv;
    }
#pragma unroll
    for (int j = 0; j < 8; ++j) red[j * 1024 + tid] = acc[j];
    __syncthreads();
    for (int s = 8; s >= 1; s >>= 1) {
        if (kc < s) {
#pragma unroll
            for (int j = 0; j < 8; ++j)
                red[j * 1024 + kc * 64 + px] += red[j * 1024 + (kc + s) * 64 + px];
        }
        __syncthreads();
    }
    if (kc == 0) {
        size_t ob = ((size_t)b * Cout + co0) * NN + n0 + px;
#pragma unroll
        for (int j = 0; j < 8; ++j) out[ob + (size_t)j * NN] = red[j * 1024 + px];
    }
}

// ======================= edge-dist tile (1024 threads) =======================
__device__ void dist_tile(const float* __restrict__ fm, float* __restrict__ dist,
                          int b, int eb, float* red) {
    int tid = threadIdx.x;
    int le = tid & 63, kc = tid >> 6;
    int kcu = __builtin_amdgcn_readfirstlane(kc);
    int e = eb * 64 + le;                  // 31*64 == 1984 exact
    int u, v; edge_uv(e, &u, &v);
    const float* fp = fm + (size_t)b * 1024 * NN;
    float s = 0.f;
    for (int c = kcu * 64; c < kcu * 64 + 64; ++c) {
        float d = fp[(size_t)c * NN + u] - fp[(size_t)c * NN + v];
        s += d * d;
    }
    red[tid] = s;
    __syncthreads();
    for (int ss = 8; ss >= 1; ss >>= 1) {
        if (kc < ss) red[kc * 64 + le] += red[(kc + ss) * 64 + le];
        __syncthreads();
    }
    if (kc == 0) dist[b * EE + e] = red[le];
}

// ============== conv 3x3 (pad 1) full-image body, 1024 threads ===============
// One thread per pixel; 8-plane LDS batches (32 KB), float4 staging.
// Accumulation order (ci ascending, 9-tap sum per ci) == 256-thr body.
__device__ void conv3x3_1024(const float* __restrict__ in, const float* __restrict__ w,
                             const float* __restrict__ gg, const float* __restrict__ bb,
                             const float* __restrict__ mm, const float* __restrict__ vv,
                             const float* __restrict__ res, float* __restrict__ out,
                             int mode, int b, int co, float* pl) {
    int tid = threadIdx.x;
    int r = tid >> 5, c = tid & 31;
    const float* ip = in + (size_t)b * 64 * NN;
    const float* wp = w + (size_t)co * 64 * 9;
    float acc = 0.f;
    for (int h = 0; h < 8; ++h) {
        __syncthreads();
        for (int i4 = tid; i4 < 2048; i4 += 1024) {       // 8 planes x 256 f4
            int ci = i4 >> 8, o4 = (i4 & 255) << 2;
            *(float4*)&pl[ci * 1024 + o4] =
                *(const float4*)&ip[(size_t)(h * 8 + ci) * NN + o4];
        }
        __syncthreads();
        for (int ci = 0; ci < 8; ++ci) {
            float wv[9];
#pragma unroll
            for (int q = 0; q < 9; ++q) wv[q] = wp[(h * 8 + ci) * 9 + q];  // uniform
            const float* P = &pl[ci * 1024];
            float s = 0.f;
#pragma unroll
            for (int dy = -1; dy <= 1; ++dy) {
                int rr = r + dy;
                if (rr < 0 || rr >= 32) continue;
#pragma unroll
                for (int dx = -1; dx <= 1; ++dx) {
                    int cc = c + dx;
                    float xv = (cc >= 0 && cc < 32) ? P[rr * 32 + cc] : 0.f;
                    s += wv[(dy + 1) * 3 + (dx + 1)] * xv;
                }
            }
            acc += s;
        }
    }
    float val;
    size_t op = ((size_t)b * 64 + co) * NN + tid;
    if (mode == 0) {
        float sc = gg[co] * rsqrtf(vv[co] + 1e-5f);
        val = acc * sc + (bb[co] - mm[co] * sc);
    } else {
        val = acc + res[op];
    }
    out[op] = fmaxf(val, 0.f);
}

// =================== 1024-thread MST state (LDS, ~57 KB) =====================
struct MstS {
    unsigned long long minkey[NN];   // later reused as off[] ints
    unsigned long long ekey[EE];     // later reused as depth ping-pong buffers
    int parent[NN], pnw[NN], pn[NN], dep[NN], scr[NN], elist[NN];
    int mstm[EE];
    int cnt, cnt2;
};

// ============ MST body: 1024 threads, reference-faithful, optimized ==========
__device__ void mst_body_1024(const float* __restrict__ dist, int b, MstS* S,
                              int* __restrict__ pn_g, int* __restrict__ maxd_g,
                              int* __restrict__ ord_g, int* __restrict__ off_g) {
    int tid = threadIdx.x;
    const float* wb = dist + b * EE;
    S->parent[tid] = tid;
    S->minkey[tid] = ~0ULL;
    for (int e = tid; e < EE; e += 1024) {
        S->mstm[e] = 0;
        S->ekey[e] = ((unsigned long long)__float_as_uint(wb[e]) << 32) | (unsigned)e;
    }
    if (tid == 0) { S->cnt = 0; S->cnt2 = 0; }
    __syncthreads();

    int r = tid >> 5, c = tid & 31;
    for (int round = 0; round < 14; ++round) {
        // node-gather min over incident cross edges; one atomic per node
        int pv = S->parent[tid];
        unsigned long long mk = ~0ULL;
        if (c < 31 && S->parent[tid + 1] != pv) {
            unsigned long long k = S->ekey[r * 31 + c]; if (k < mk) mk = k;
        }
        if (c > 0 && S->parent[tid - 1] != pv) {
            unsigned long long k = S->ekey[r * 31 + c - 1]; if (k < mk) mk = k;
        }
        if (r < 31 && S->parent[tid + 32] != pv) {
            unsigned long long k = S->ekey[992 + r * 32 + c]; if (k < mk) mk = k;
        }
        if (r > 0 && S->parent[tid - 32] != pv) {
            unsigned long long k = S->ekey[992 + (r - 1) * 32 + c]; if (k < mk) mk = k;
        }
        if (mk != ~0ULL) atomicMin(&S->minkey[pv], mk);
        __syncthreads();
        int np;
        unsigned long long sel = S->minkey[tid];
        S->minkey[tid] = ~0ULL;            // fused reset (only tid reads slot tid)
        if (sel != ~0ULL) {
            int e = (int)(sel & 0xffffffffULL);
            if (atomicExch(&S->mstm[e], 1) == 0) atomicAdd(&S->cnt, 1);
            int eu, ev; edge_uv(e, &eu, &ev);
            int cu = S->parent[eu], cv = S->parent[ev];
            np = (cu == tid) ? cv : cu;
        } else np = tid;                  // reference: re-singleton when !valid
        S->pnw[tid] = np;
        __syncthreads();
        int q = S->pnw[tid];
        int pq = S->pnw[q];
        S->parent[tid] = (pq == tid && tid < q) ? tid : q;   // 2-cycle break
        __syncthreads();                   // parent fully written before flatten
        for (;;) {                         // adaptive in-place 2-jump flatten
            int p = S->parent[tid];
            p = S->parent[p];
            p = S->parent[p];
            S->parent[tid] = p;
            int ch = (S->parent[p] != p);
            if (!__syncthreads_or(ch)) break;
        }
        if (S->cnt == NN - 1) break;      // mask complete => final (cut property)
    }

    for (int e = tid; e < EE; e += 1024)
        if (S->mstm[e]) { int s = atomicAdd(&S->cnt2, 1); S->elist[s] = e; }
    __syncthreads();
    int ecnt = S->cnt2;

    // BFS from node 0: 16 unsynced volatile scans per barrier epoch
    S->pn[tid] = (tid == 0) ? 0 : -1;
    __syncthreads();
    volatile int* vpn = S->pn;
    int myu = 0, myv = 0; bool have = tid < ecnt;
    if (have) { edge_uv(S->elist[tid], &myu, &myv); }
    for (;;) {
        int ch = 0;
        for (int s = 0; s < 16; ++s) {
            if (have) {
                int pu = vpn[myu], pv = vpn[myv];
                if (pu >= 0 && pv < 0)      { vpn[myv] = myu; ch = 1; }
                else if (pv >= 0 && pu < 0) { vpn[myu] = myv; ch = 1; }
            }
        }
        if (!__syncthreads_or(ch)) break;
    }
    int incomplete = __syncthreads_or(S->pn[tid] < 0);

    // depth: pointer doubling, -1 wraps to N-1; disjoint ping-pong, 1 barrier/it;
    // adaptive exit exact when BFS reached all nodes (pointers stabilize at 0).
    S->dep[tid] = (tid != 0) ? 1 : 0;
    S->pnw[tid] = S->pn[tid];
    __syncthreads();
    int* dA = S->dep;  int* dB = (int*)S->ekey;
    int* pA = S->pnw;  int* pB = ((int*)S->ekey) + NN;
    for (int it = 0; it < 12; ++it) {
        int p = pA[tid];
        int j = (p < 0) ? (NN + p) : p;
        dB[tid] = dA[tid] + dA[j];
        int nx = pA[j];
        pB[tid] = nx;
        int fin = (!incomplete) && (!__syncthreads_or(nx != 0));
        int* t = dA; dA = dB; dB = t;
        t = pA; pA = pB; pB = t;
        if (fin) break;                    // all pointers at root: depth stable
    }
    if (tid == 0) S->cnt = 0;
    __syncthreads();
    int d = dA[tid];
    if (d >= 1 && d <= NN - 1) atomicMax(&S->cnt, d);
    __syncthreads();
    int maxd = S->cnt;

    // counting sort by depth (bucket 0 = root + out-of-range)
    S->scr[tid] = 0;
    __syncthreads();
    int bkt = (tid != 0 && d >= 1 && d <= NN - 1) ? d : 0;
    atomicAdd(&S->scr[bkt], 1);
    __syncthreads();
    int cntv = S->scr[tid];
    int lane = tid & 63, wid = tid >> 6;
    int x = cntv;
    for (int d2 = 1; d2 < 64; d2 <<= 1) {
        int y = __shfl_up(x, d2, 64);
        if (lane >= d2) x += y;
    }
    if (lane == 63) S->pnw[wid] = x;       // wave totals
    __syncthreads();
    if (tid < 16) {
        int off = 0;
        for (int i = 0; i < tid; ++i) off += S->pnw[i];
        S->parent[tid] = off;
    }
    __syncthreads();
    int excl = x - cntv + S->parent[wid];
    int* mi = (int*)S->minkey;             // minkey free now
    mi[tid] = excl;
    S->scr[tid] = excl;                    // running counters
    __syncthreads();
    int pos = atomicAdd(&S->scr[bkt], 1);
    S->elist[pos] = tid;                   // elist reused as ord
    __syncthreads();

    pn_g[b * NN + tid]    = S->pn[tid];
    ord_g[b * NN + tid]   = S->elist[tid];
    off_g[b * 1025 + tid] = mi[tid];
    if (tid == 0) { off_g[b * 1025 + 1024] = NN; maxd_g[b] = maxd; }
}

// =============== tree filter body: ONE WAVE, level-list driven ===============
struct TfSmem { float agg[NN * 3]; float wv[NN]; int jj[NN]; int ords[NN]; int offs[1025]; };
__device__ void treefilter_wave(const float* __restrict__ feat, const float* __restrict__ emb,
                                const int* __restrict__ pn_g, const int* __restrict__ ord_g,
                                const int* __restrict__ off_g, const int* __restrict__ maxd_g,
                                float* __restrict__ tfout, int b, int g, int sub, TfSmem* S) {
    int lane = threadIdx.x;
    const float* eb = emb + ((size_t)b * 32 + g * 8) * NN;
    int c0 = g * 16 + sub * 2;
    const float* fb = feat + ((size_t)b * 64 + c0) * NN;
    for (int k = 0; k < 16; ++k) {
        int v = lane + k * 64;
        int p = pn_g[b * NN + v];
        int j = (p < 0) ? (NN + p) : p;        // JAX negative indexing
        S->jj[v] = j;
        float s = 0.f;
#pragma unroll
        for (int q = 0; q < 8; ++q) {
            float d = eb[(size_t)q * NN + v] - eb[(size_t)q * NN + j];
            s += d * d;
        }
        S->wv[v] = expf(-s);
        S->agg[v * 3 + 0] = fb[v];
        S->agg[v * 3 + 1] = fb[NN + v];
        S->agg[v * 3 + 2] = 1.f;
        S->ords[v] = ord_g[b * NN + v];
        S->offs[v] = off_g[b * 1025 + v];
    }
    if (lane == 0) S->offs[1024] = NN;
    int maxdep = maxd_g[b];
    for (int lev = maxdep; lev >= 1; --lev) {             // up sweep
        int s0 = S->offs[lev], s1 = S->offs[lev + 1];
        for (int i = s0 + lane; i < s1; i += 64) {
            int v = S->ords[i]; int j = S->jj[v]; float w = S->wv[v];
            atomicAdd(&S->agg[j * 3 + 0], w * S->agg[v * 3 + 0]);
            atomicAdd(&S->agg[j * 3 + 1], w * S->agg[v * 3 + 1]);
            atomicAdd(&S->agg[j * 3 + 2], w * S->agg[v * 3 + 2]);
        }
    }
    for (int lev = 1; lev <= maxdep; ++lev) {             // down sweep (in place)
        int s0 = S->offs[lev], s1 = S->offs[lev + 1];
        for (int i = s0 + lane; i < s1; i += 64) {
            int v = S->ords[i]; int j = S->jj[v]; float w = S->wv[v];
#pragma unroll
            for (int c = 0; c < 3; ++c) {
                float a = S->agg[v * 3 + c];
                S->agg[v * 3 + c] = a + w * (S->agg[j * 3 + c] - w * a);
            }
        }
    }
    float* ob = tfout + ((size_t)b * 64 + c0) * NN;
    for (int k = 0; k < 16; ++k) {
        int v = lane + k * 64;
        float inv = 1.f / S->agg[v * 3 + 2];
        ob[v]      = S->agg[v * 3 + 0] * inv;
        ob[NN + v] = S->agg[v * 3 + 1] * inv;
    }
}

// ================================ K1 mega ====================================
// Flags: C[0]=dist, C[1]/C[2]=mst per batch, C[3]=embed, C[4]=conv1x1, C[5]=3x3a
union K1S { float red[8192]; float pl[8192]; MstS m; TfSmem t; };
__global__ __launch_bounds__(1024) void k1_mega(
    const float* __restrict__ fm, const float* __restrict__ last_fm,
    const float* __restrict__ lat_w1, const float* __restrict__ emb_w,
    const float* __restrict__ lat_w3a,
    const float* __restrict__ lat_g, const float* __restrict__ lat_b,
    const float* __restrict__ lat_m, const float* __restrict__ lat_v,
    const float* __restrict__ lat_w3b,
    float* __restrict__ lat_x1, float* __restrict__ lat_t1,
    float* __restrict__ latent, float* __restrict__ dist,
    float* __restrict__ embed, float* __restrict__ tfout,
    int* __restrict__ pn_g, int* __restrict__ maxd_g,
    int* __restrict__ ord_g, int* __restrict__ off_g, int* __restrict__ C) {
    __shared__ __align__(16) K1S s;
    int bx = blockIdx.x;
    if (bx < 62) {                              // dist producers
        dist_tile(fm, dist, bx / 31, bx % 31, s.red);
        signal_done(&C[0]);
    } else if (bx < 318) {                      // big conv1x1 producers
        int i = bx - 62, b = i >> 7, r = i & 127;
        conv1x1_tile(fm, nullptr, lat_w1, lat_x1, 1024, 64,
                     b, (r >> 4) * 8, (r & 15) * 64, s.red);
        signal_done(&C[4]);
    } else if (bx < 446) {                      // embed producers
        int i = bx - 318, b = i >> 6, r = i & 63;
        conv1x1_tile(last_fm, nullptr, emb_w, embed, 64, 32,
                     b, (r >> 4) * 8, (r & 15) * 64, s.red);
        signal_done(&C[3]);
    } else if (bx < 448) {                      // MST (consumes dist)
        int b = bx - 446;
        wait_for(&C[0], 62);
        mst_body_1024(dist, b, &s.m, pn_g, maxd_g, ord_g, off_g);
        signal_done(&C[1 + b]);
    } else if (bx < 576) {                      // conv3x3a (consumes conv1x1)
        wait_for(&C[4], 256);
        int t = bx - 448;
        conv3x3_1024(lat_x1, lat_w3a, lat_g, lat_b, lat_m, lat_v,
                     nullptr, lat_t1, 0, t >> 6, t & 63, s.pl);
        signal_done(&C[5]);
    } else if (bx < 704) {                      // conv3x3b (consumes 3x3a)
        wait_for(&C[5], 128);
        int t = bx - 576;
        conv3x3_1024(lat_t1, lat_w3b, nullptr, nullptr, nullptr, nullptr,
                     lat_x1, latent, 1, t >> 6, t & 63, s.pl);
    } else {                                    // treefilter (consumes MST+embed)
        int i = bx - 704, b = i >> 5;
        wait_for(&C[1 + b], 1);
        wait_for(&C[3], 128);
        if (threadIdx.x < 64)
            treefilter_wave(last_fm, embed, pn_g, ord_g, off_g, maxd_g, tfout,
                            b, (i >> 3) & 3, i & 7, &s.t);
    }
}

// ================================ K2 mega ====================================
// C[6]=ref1x1 count, C[7]=ref3x3a count
union K2S { float red[8192]; float pl[8192]; };
__global__ __launch_bounds__(1024) void k2_mega(
    const float* __restrict__ latent, const float* __restrict__ tfout,
    const float* __restrict__ ref_w1, const float* __restrict__ ref_w3a,
    const float* __restrict__ ref_g, const float* __restrict__ ref_b,
    const float* __restrict__ ref_m, const float* __restrict__ ref_v,
    const float* __restrict__ ref_w3b,
    float* __restrict__ ref_x1, float* __restrict__ ref_t1,
    float* __restrict__ out, int* __restrict__ C) {
    __shared__ __align__(16) K2S s;
    int bx = blockIdx.x;
    if (bx < 256) {                             // ref conv1x1 on latent+tfout
        int b = bx >> 7, r = bx & 127;
        conv1x1_tile(latent, tfout, ref_w1, ref_x1, 64, 64,
                     b, (r >> 4) * 8, (r & 15) * 64, s.red);
        signal_done(&C[6]);
    } else if (bx < 384) {                      // ref conv3x3a
        wait_for(&C[6], 256);
        int t = bx - 256;
        conv3x3_1024(ref_x1, ref_w3a, ref_g, ref_b, ref_m, ref_v,
                     nullptr, ref_t1, 0, t >> 6, t & 63, s.pl);
        signal_done(&C[7]);
    } else {                                    // ref conv3x3b -> out
        wait_for(&C[7], 128);
        int t = bx - 384;
        conv3x3_1024(ref_t1, ref_w3b, nullptr, nullptr, nullptr, nullptr,
                     ref_x1, out, 1, t >> 6, t & 63, s.pl);
    }
}

// ----------------------------- host launcher ---------------------------------
extern "C" void kernel_launch(void* const* d_in, const int* in_sizes, int n_in,
                              void* d_out, int out_size, void* d_ws, size_t ws_size,
                              hipStream_t stream) {
    const float* fm      = (const float*)d_in[0];
    const float* last_fm = (const float*)d_in[1];
    const float* lat_w1  = (const float*)d_in[2];
    const float* lat_w3a = (const float*)d_in[3];
    const float* lat_g   = (const float*)d_in[4];
    const float* lat_b   = (const float*)d_in[5];
    const float* lat_m   = (const float*)d_in[6];
    const float* lat_v   = (const float*)d_in[7];
    const float* lat_w3b = (const float*)d_in[8];
    const float* ref_w1  = (const float*)d_in[9];
    const float* ref_w3a = (const float*)d_in[10];
    const float* ref_g   = (const float*)d_in[11];
    const float* ref_b   = (const float*)d_in[12];
    const float* ref_m   = (const float*)d_in[13];
    const float* ref_v   = (const float*)d_in[14];
    const float* ref_w3b = (const float*)d_in[15];
    const float* emb_w   = (const float*)d_in[16];
    float* out = (float*)d_out;

    float* ws      = (float*)d_ws;
    float* lat_x1  = ws;                  // 2*64*1024
    float* lat_t1  = lat_x1 + 131072;
    float* latent  = lat_t1 + 131072;
    float* dist    = latent + 131072;     // 2*1984 (pad 4096)
    float* embed   = dist + 4096;         // 2*32*1024
    float* tfout   = embed + 65536;
    float* ref_x1  = tfout + 131072;
    float* ref_t1  = ref_x1 + 131072;
    int*   pn      = (int*)(ref_t1 + 131072);  // 2*1024
    int*   ordg    = pn + 2048;                // 2*1024
    int*   offg    = ordg + 2048;              // 2*1025 (pad 2080)
    int*   maxd    = offg + 2080;              // 2 (pad 8)
    int*   C       = maxd + 8;                 // 8 handshake counters

    // zero the handshake counters (graph-capture-legal async memset)
    hipMemsetAsync(C, 0, 8 * sizeof(int), stream);

    // K1: dist + conv1x1big + embed (producers) || MST, conv3x3a, conv3x3b,
    //     treefilter (in-kernel consumers via device-scope flags)
    k1_mega<<<768, 1024, 0, stream>>>(fm, last_fm, lat_w1, emb_w, lat_w3a,
                                      lat_g, lat_b, lat_m, lat_v, lat_w3b,
                                      lat_x1, lat_t1, latent, dist, embed, tfout,
                                      pn, maxd, ordg, offg, C);
    // K2: ref1x1 -> ref3x3a -> ref3x3b (in-kernel pipeline)
    k2_mega<<<512, 1024, 0, stream>>>(latent, tfout, ref_w1, ref_w3a,
                                      ref_g, ref_b, ref_m, ref_v, ref_w3b,
                                      ref_x1, ref_t1, out, C);
}

// Round 13
// 244.337 us; speedup vs baseline: 4.4040x; 4.4040x over previous
//
#include <hip/hip_runtime.h>
#include <hip/hip_bf16.h>

#define NN 1024   // nodes = 32*32
#define EE 1984   // grid edges

// ---------------- edge index -> endpoints (matches grid_edges) ----------------
__device__ __forceinline__ void edge_uv(int e, int* u, int* v) {
    if (e < 992) {             // horizontal: idx[:, :-1] -> idx[:, 1:]
        int r = e / 31, c = e - r * 31;
        *u = r * 32 + c; *v = *u + 1;
    } else {                   // vertical: idx[:-1, :] -> idx[1:, :]
        *u = e - 992; *v = *u + 32;
    }
}

// ======================= conv 1x1 tile (1024 threads) ========================
__device__ void conv1x1_tile(const float* __restrict__ in, const float* __restrict__ in2,
                             const float* __restrict__ w,
                             float* __restrict__ out, int CIN, int Cout,
                             int b, int co0, int n0, float* red) {
    int tid = threadIdx.x;
    int px = tid & 63, kc = tid >> 6;
    int kcu = __builtin_amdgcn_readfirstlane(kc);   // wave-uniform -> s_loads for w
    int KCH = CIN >> 4;
    size_t ibase = (size_t)b * CIN * NN + n0 + px;
    const float* wr = w + (size_t)co0 * CIN;
    float acc[8] = {0.f,0.f,0.f,0.f,0.f,0.f,0.f,0.f};
    for (int ci = kcu * KCH; ci < kcu * KCH + KCH; ++ci) {
        float xv = in[ibase + (size_t)ci * NN];
        if (in2) xv += in2[ibase + (size_t)ci * NN];
#pragma unroll
        for (int j = 0; j < 8; ++j)
            acc[j] += wr[j * CIN + ci] * xv;
    }
#pragma unroll
    for (int j = 0; j < 8; ++j) red[j * 1024 + tid] = acc[j];
    __syncthreads();
    for (int s = 8; s >= 1; s >>= 1) {
        if (kc < s) {
#pragma unroll
            for (int j = 0; j < 8; ++j)
                red[j * 1024 + kc * 64 + px] += red[j * 1024 + (kc + s) * 64 + px];
        }
        __syncthreads();
    }
    if (kc == 0) {
        size_t ob = ((size_t)b * Cout + co0) * NN + n0 + px;
#pragma unroll
        for (int j = 0; j < 8; ++j) out[ob + (size_t)j * NN] = red[j * 1024 + px];
    }
}

// ======================= edge-dist tile (1024 threads) =======================
__device__ void dist_tile(const float* __restrict__ fm, float* __restrict__ dist,
                          int b, int eb, float* red) {
    int tid = threadIdx.x;
    int le = tid & 63, kc = tid >> 6;
    int kcu = __builtin_amdgcn_readfirstlane(kc);
    int e = eb * 64 + le;                  // 31*64 == 1984 exact
    int u, v; edge_uv(e, &u, &v);
    const float* fp = fm + (size_t)b * 1024 * NN;
    float s = 0.f;
    for (int c = kcu * 64; c < kcu * 64 + 64; ++c) {
        float d = fp[(size_t)c * NN + u] - fp[(size_t)c * NN + v];
        s += d * d;
    }
    red[tid] = s;
    __syncthreads();
    for (int ss = 8; ss >= 1; ss >>= 1) {
        if (kc < ss) red[kc * 64 + le] += red[(kc + ss) * 64 + le];
        __syncthreads();
    }
    if (kc == 0) dist[b * EE + e] = red[le];
}

// ================== conv 3x3 body (256 threads, 2-half staging) ==============
__device__ void conv3x3_body(const float* __restrict__ in, const float* __restrict__ w,
                             const float* __restrict__ gg, const float* __restrict__ bb,
                             const float* __restrict__ mm, const float* __restrict__ vv,
                             const float* __restrict__ res, float* __restrict__ out,
                             int mode, int b, int co, int r0, float* pl) {
    int tid = threadIdx.x;
    const float* ip = in + (size_t)b * 64 * NN;
    const float* wp = w + (size_t)co * 64 * 9;
    int r = tid >> 5, c = tid & 31;
    float acc = 0.f;
    for (int h = 0; h < 2; ++h) {
        __syncthreads();
        for (int i4 = tid; i4 < 32 * 80; i4 += 256) {    // float4 staging
            int ci = i4 / 80, o = i4 - ci * 80;
            int row = r0 - 1 + (o >> 3), c4 = (o & 7) << 2;
            float4 val = make_float4(0.f, 0.f, 0.f, 0.f);
            if (row >= 0 && row < 32)
                val = *(const float4*)&ip[(size_t)(h * 32 + ci) * NN + row * 32 + c4];
            *(float4*)&pl[ci * 320 + (o >> 3) * 32 + c4] = val;
        }
        __syncthreads();
        for (int ci = 0; ci < 32; ++ci) {
            float wv[9];
#pragma unroll
            for (int q = 0; q < 9; ++q) wv[q] = wp[(h * 32 + ci) * 9 + q];  // uniform
            float s = 0.f;
#pragma unroll
            for (int dy = 0; dy < 3; ++dy) {
                const float* row = &pl[ci * 320 + (r + dy) * 32];
#pragma unroll
                for (int dx = -1; dx <= 1; ++dx) {
                    int cc = c + dx;
                    float xv = (cc >= 0 && cc < 32) ? row[cc] : 0.f;
                    s += wv[dy * 3 + (dx + 1)] * xv;
                }
            }
            acc += s;
        }
    }
    float val;
    size_t op = ((size_t)b * 64 + co) * NN + r0 * 32 + tid;
    if (mode == 0) {
        float sc = gg[co] * rsqrtf(vv[co] + 1e-5f);
        val = acc * sc + (bb[co] - mm[co] * sc);
    } else {
        val = acc + res[op];
    }
    out[op] = fmaxf(val, 0.f);
}

// =================== 1024-thread MST state (LDS, ~57 KB) =====================
struct MstS {
    unsigned long long minkey[NN];   // later reused as off[] ints
    unsigned long long ekey[EE];     // later reused as depth ping-pong buffers
    int parent[NN], pnw[NN], pn[NN], dep[NN], scr[NN], elist[NN];
    int mstm[EE];
    int cnt, cnt2;
};

// ============ MST body: 1024 threads, reference-faithful, optimized ==========
// Re-singleton Boruvka (exact reference emulation), barrier-minimized:
//  - node-gather min (1 atomic/node)
//  - pnew / 2-cycle break computed directly from (minkey, P); next labels to a
//    ping-pong array
//  - minkey reset folded into the flatten's first iteration
//  - adaptive in-place 3-jump flatten to fixed point (== ref's 12 doublings)
//  - early exit at N-1 mask edges (cut property)
// BFS: 24 unsynced volatile scans/epoch (write-once race benign in a tree).
// Depth: pointer doubling, JAX -1 -> N-1 wrap, disjoint ping-pong with an
// UNCONDITIONAL barrier every iteration (R12 bug: short-circuit skipped it
// when the forest was incomplete -> racy depths); adaptive exit only when
// BFS reached all nodes. Counting sort -> level lists.
__device__ void mst_body_1024(const float* __restrict__ dist, int b, MstS* S,
                              int* __restrict__ pn_g, int* __restrict__ maxd_g,
                              int* __restrict__ ord_g, int* __restrict__ off_g) {
    int tid = threadIdx.x;
    const float* wb = dist + b * EE;
    S->parent[tid] = tid;
    S->minkey[tid] = ~0ULL;
    for (int e = tid; e < EE; e += 1024) {
        S->mstm[e] = 0;
        S->ekey[e] = ((unsigned long long)__float_as_uint(wb[e]) << 32) | (unsigned)e;
    }
    if (tid == 0) { S->cnt = 0; S->cnt2 = 0; }
    __syncthreads();

    int r = tid >> 5, c = tid & 31;
    int* P = S->parent;                    // current labels
    int* Q = S->pnw;                       // next labels
    for (int round = 0; round < 14; ++round) {
        // phase A: node-gather min over incident cross edges; 1 atomic per node
        int pv = P[tid];
        unsigned long long mk = ~0ULL;
        if (c < 31 && P[tid + 1] != pv) {
            unsigned long long k = S->ekey[r * 31 + c]; if (k < mk) mk = k;
        }
        if (c > 0 && P[tid - 1] != pv) {
            unsigned long long k = S->ekey[r * 31 + c - 1]; if (k < mk) mk = k;
        }
        if (r < 31 && P[tid + 32] != pv) {
            unsigned long long k = S->ekey[992 + r * 32 + c]; if (k < mk) mk = k;
        }
        if (r > 0 && P[tid - 32] != pv) {
            unsigned long long k = S->ekey[992 + (r - 1) * 32 + c]; if (k < mk) mk = k;
        }
        if (mk != ~0ULL) atomicMin(&S->minkey[pv], mk);
        __syncthreads();                   // barrier 1

        // phase B: np(v), np(np(v)) directly from minkey+P; write broken -> Q
        unsigned long long sel = S->minkey[tid];
        int np;
        if (sel != ~0ULL) {
            int e = (int)(sel & 0xffffffffULL);
            if (atomicExch(&S->mstm[e], 1) == 0) atomicAdd(&S->cnt, 1);
            int eu, ev; edge_uv(e, &eu, &ev);
            int cu = P[eu], cv = P[ev];
            np = (cu == tid) ? cv : cu;
        } else np = tid;                  // reference: re-singleton when !valid
        int q = np, pq;
        if (q == tid) pq = tid;
        else {
            unsigned long long selq = S->minkey[q];
            if (selq != ~0ULL) {
                int e2 = (int)(selq & 0xffffffffULL);
                int eu2, ev2; edge_uv(e2, &eu2, &ev2);
                int cu2 = P[eu2], cv2 = P[ev2];
                pq = (cu2 == q) ? cv2 : cu2;
            } else pq = q;
        }
        Q[tid] = (pq == tid && tid < q) ? tid : q;   // 2-cycle break
        __syncthreads();                   // barrier 2

        // flatten Q in place (3-jump, adaptive); fold minkey reset into iter 0
        bool first = true;
        for (;;) {
            if (first) { S->minkey[tid] = ~0ULL; first = false; }
            int p = Q[tid];
            p = Q[p]; p = Q[p]; p = Q[p];
            Q[tid] = p;
            int ch = (Q[p] != p);
            if (!__syncthreads_or(ch)) break;
        }
        if (S->cnt == NN - 1) break;       // mask complete => final (cut property)
        int* t = P; P = Q; Q = t;          // next round's labels
    }

    for (int e = tid; e < EE; e += 1024)
        if (S->mstm[e]) { int s = atomicAdd(&S->cnt2, 1); S->elist[s] = e; }
    __syncthreads();
    int ecnt = S->cnt2;

    // BFS from node 0: 24 unsynced volatile scans per barrier epoch
    S->pn[tid] = (tid == 0) ? 0 : -1;
    __syncthreads();
    volatile int* vpn = S->pn;
    int myu = 0, myv = 0; bool have = tid < ecnt;
    if (have) { edge_uv(S->elist[tid], &myu, &myv); }
    for (;;) {
        int ch = 0;
        for (int s = 0; s < 24; ++s) {
            if (have) {
                int pu = vpn[myu], pv = vpn[myv];
                if (pu >= 0 && pv < 0)      { vpn[myv] = myu; ch = 1; }
                else if (pv >= 0 && pu < 0) { vpn[myu] = myv; ch = 1; }
            }
        }
        if (!__syncthreads_or(ch)) break;
    }
    int incomplete = __syncthreads_or(S->pn[tid] < 0);

    // depth: pointer doubling, -1 wraps to N-1; disjoint ping-pong.
    // UNCONDITIONAL barrier every iteration; adaptive exit only if complete.
    S->dep[tid] = (tid != 0) ? 1 : 0;
    S->pnw[tid] = S->pn[tid];
    __syncthreads();
    int* dA = S->dep;  int* dB = (int*)S->ekey;
    int* pA = S->pnw;  int* pB = ((int*)S->ekey) + NN;
    for (int it = 0; it < 12; ++it) {
        int p = pA[tid];
        int j = (p < 0) ? (NN + p) : p;
        dB[tid] = dA[tid] + dA[j];
        int nx = pA[j];
        pB[tid] = nx;
        int anynz = __syncthreads_or(nx != 0);   // barrier ALWAYS executes
        int* t = dA; dA = dB; dB = t;
        t = pA; pA = pB; pB = t;
        if (!incomplete && !anynz) break;  // all pointers at root: depth stable
    }
    if (tid == 0) S->cnt = 0;
    __syncthreads();
    int d = dA[tid];
    if (d >= 1 && d <= NN - 1) atomicMax(&S->cnt, d);
    __syncthreads();
    int maxd = S->cnt;

    // counting sort by depth (bucket 0 = root + out-of-range)
    S->scr[tid] = 0;
    __syncthreads();
    int bkt = (tid != 0 && d >= 1 && d <= NN - 1) ? d : 0;
    atomicAdd(&S->scr[bkt], 1);
    __syncthreads();
    int cntv = S->scr[tid];
    int lane = tid & 63, wid = tid >> 6;
    int x = cntv;
    for (int d2 = 1; d2 < 64; d2 <<= 1) {
        int y = __shfl_up(x, d2, 64);
        if (lane >= d2) x += y;
    }
    if (lane == 63) S->pnw[wid] = x;       // wave totals
    __syncthreads();
    if (tid < 16) {
        int off = 0;
        for (int i = 0; i < tid; ++i) off += S->pnw[i];
        S->parent[tid] = off;
    }
    __syncthreads();
    int excl = x - cntv + S->parent[wid];
    int* mi = (int*)S->minkey;             // minkey free now
    mi[tid] = excl;
    S->scr[tid] = excl;                    // running counters
    __syncthreads();
    int pos = atomicAdd(&S->scr[bkt], 1);
    S->elist[pos] = tid;                   // elist reused as ord
    __syncthreads();

    pn_g[b * NN + tid]    = S->pn[tid];
    ord_g[b * NN + tid]   = S->elist[tid];
    off_g[b * 1025 + tid] = mi[tid];
    if (tid == 0) { off_g[b * 1025 + 1024] = NN; maxd_g[b] = maxd; }
}

// =============== tree filter body: ONE WAVE, level-list driven ===============
struct TfSmem { float agg[NN * 3]; float wv[NN]; int jj[NN]; int ords[NN]; int offs[1025]; };
__device__ void treefilter_wave(const float* __restrict__ feat, const float* __restrict__ emb,
                                const int* __restrict__ pn_g, const int* __restrict__ ord_g,
                                const int* __restrict__ off_g, const int* __restrict__ maxd_g,
                                float* __restrict__ tfout, int b, int g, int sub, TfSmem* S) {
    int lane = threadIdx.x;
    const float* eb = emb + ((size_t)b * 32 + g * 8) * NN;
    int c0 = g * 16 + sub * 2;
    const float* fb = feat + ((size_t)b * 64 + c0) * NN;
    for (int k = 0; k < 16; ++k) {
        int v = lane + k * 64;
        int p = pn_g[b * NN + v];
        int j = (p < 0) ? (NN + p) : p;        // JAX negative indexing
        S->jj[v] = j;
        float s = 0.f;
#pragma unroll
        for (int q = 0; q < 8; ++q) {
            float d = eb[(size_t)q * NN + v] - eb[(size_t)q * NN + j];
            s += d * d;
        }
        S->wv[v] = expf(-s);
        S->agg[v * 3 + 0] = fb[v];
        S->agg[v * 3 + 1] = fb[NN + v];
        S->agg[v * 3 + 2] = 1.f;
        S->ords[v] = ord_g[b * NN + v];
        S->offs[v] = off_g[b * 1025 + v];
    }
    if (lane == 0) S->offs[1024] = NN;
    int maxdep = maxd_g[b];
    for (int lev = maxdep; lev >= 1; --lev) {             // up sweep
        int s0 = S->offs[lev], s1 = S->offs[lev + 1];
        for (int i = s0 + lane; i < s1; i += 64) {
            int v = S->ords[i]; int j = S->jj[v]; float w = S->wv[v];
            atomicAdd(&S->agg[j * 3 + 0], w * S->agg[v * 3 + 0]);
            atomicAdd(&S->agg[j * 3 + 1], w * S->agg[v * 3 + 1]);
            atomicAdd(&S->agg[j * 3 + 2], w * S->agg[v * 3 + 2]);
        }
    }
    for (int lev = 1; lev <= maxdep; ++lev) {             // down sweep (in place)
        int s0 = S->offs[lev], s1 = S->offs[lev + 1];
        for (int i = s0 + lane; i < s1; i += 64) {
            int v = S->ords[i]; int j = S->jj[v]; float w = S->wv[v];
#pragma unroll
            for (int c = 0; c < 3; ++c) {
                float a = S->agg[v * 3 + c];
                S->agg[v * 3 + c] = a + w * (S->agg[j * 3 + c] - w * a);
            }
        }
    }
    float* ob = tfout + ((size_t)b * 64 + c0) * NN;
    for (int k = 0; k < 16; ++k) {
        int v = lane + k * 64;
        float inv = 1.f / S->agg[v * 3 + 2];
        ob[v]      = S->agg[v * 3 + 0] * inv;
        ob[NN + v] = S->agg[v * 3 + 1] * inv;
    }
}

// ============================ kernel 0: dist =================================
__global__ __launch_bounds__(1024) void k0_dist(
    const float* __restrict__ fm, float* __restrict__ dist) {
    __shared__ float red[1024];
    int i = blockIdx.x;                    // 62 blocks: 31 eb x 2 b
    dist_tile(fm, dist, i / 31, i % 31, red);
}

// ============ kernel 1: MST + big conv1x1 + embed conv (1024 thr) ============
union K1S { float red[8192]; MstS m; };
__global__ __launch_bounds__(1024) void k1_fused(
    const float* __restrict__ fm, const float* __restrict__ last_fm,
    const float* __restrict__ lat_w1, const float* __restrict__ emb_w,
    float* __restrict__ lat_x1, float* __restrict__ embed,
    const float* __restrict__ dist, int* __restrict__ pn_g,
    int* __restrict__ maxd_g, int* __restrict__ ord_g, int* __restrict__ off_g) {
    __shared__ __align__(16) K1S s;
    int bx = blockIdx.x;
    if (bx < 2) {
        mst_body_1024(dist, bx, &s.m, pn_g, maxd_g, ord_g, off_g);
    } else if (bx < 258) {
        int i = bx - 2, b = i >> 7, r = i & 127;
        conv1x1_tile(fm, nullptr, lat_w1, lat_x1, 1024, 64,
                     b, (r >> 4) * 8, (r & 15) * 64, s.red);
    } else {
        int i = bx - 258, b = i >> 6, r = i & 63;
        conv1x1_tile(last_fm, nullptr, emb_w, embed, 64, 32,
                     b, (r >> 4) * 8, (r & 15) * 64, s.red);
    }
}

// ============== kernel 2: treefilter + conv3x3a (256 thr) ====================
union K2S { float pl[32 * 320]; TfSmem t; };
__global__ __launch_bounds__(256) void k2_fused(
    const float* __restrict__ lat_x1, const float* __restrict__ lat_w3a,
    const float* __restrict__ lat_g, const float* __restrict__ lat_b,
    const float* __restrict__ lat_m, const float* __restrict__ lat_v,
    float* __restrict__ lat_t1,
    const float* __restrict__ last_fm, const float* __restrict__ embed,
    const int* __restrict__ pn_g, const int* __restrict__ ord_g,
    const int* __restrict__ off_g, const int* __restrict__ maxd_g,
    float* __restrict__ tfout) {
    __shared__ __align__(16) K2S s;
    int bx = blockIdx.x;
    if (bx < 64) {                          // TF first: serial chains start ASAP
        if (threadIdx.x >= 64) return;
        treefilter_wave(last_fm, embed, pn_g, ord_g, off_g, maxd_g, tfout,
                        bx >> 5, (bx >> 3) & 3, bx & 7, &s.t);
    } else {
        int i = bx - 64, b = i >> 8, co = (i >> 2) & 63, r0 = (i & 3) * 8;
        conv3x3_body(lat_x1, lat_w3a, lat_g, lat_b, lat_m, lat_v,
                     nullptr, lat_t1, 0, b, co, r0, s.pl);
    }
}

// ===================== standalone conv kernels ===============================
__global__ __launch_bounds__(256) void conv3x3_kernel(
    const float* __restrict__ in, const float* __restrict__ w,
    const float* __restrict__ gg, const float* __restrict__ bb,
    const float* __restrict__ mm, const float* __restrict__ vv,
    const float* __restrict__ res, float* __restrict__ out, int mode) {
    __shared__ __align__(16) float pl[32 * 320];
    conv3x3_body(in, w, gg, bb, mm, vv, res, out, mode,
                 blockIdx.z, blockIdx.y, blockIdx.x * 8, pl);
}

__global__ __launch_bounds__(1024) void conv1x1_add_kernel(
    const float* __restrict__ in, const float* __restrict__ in2,
    const float* __restrict__ w, float* __restrict__ out, int CIN, int Cout) {
    __shared__ float red[8192];
    conv1x1_tile(in, in2, w, out, CIN, Cout, blockIdx.z, blockIdx.y * 8,
                 blockIdx.x * 64, red);
}

// ----------------------------- host launcher ---------------------------------
extern "C" void kernel_launch(void* const* d_in, const int* in_sizes, int n_in,
                              void* d_out, int out_size, void* d_ws, size_t ws_size,
                              hipStream_t stream) {
    const float* fm      = (const float*)d_in[0];
    const float* last_fm = (const float*)d_in[1];
    const float* lat_w1  = (const float*)d_in[2];
    const float* lat_w3a = (const float*)d_in[3];
    const float* lat_g   = (const float*)d_in[4];
    const float* lat_b   = (const float*)d_in[5];
    const float* lat_m   = (const float*)d_in[6];
    const float* lat_v   = (const float*)d_in[7];
    const float* lat_w3b = (const float*)d_in[8];
    const float* ref_w1  = (const float*)d_in[9];
    const float* ref_w3a = (const float*)d_in[10];
    const float* ref_g   = (const float*)d_in[11];
    const float* ref_b   = (const float*)d_in[12];
    const float* ref_m   = (const float*)d_in[13];
    const float* ref_v   = (const float*)d_in[14];
    const float* ref_w3b = (const float*)d_in[15];
    const float* emb_w   = (const float*)d_in[16];
    float* out = (float*)d_out;

    float* ws      = (float*)d_ws;
    float* lat_x1  = ws;                  // 2*64*1024
    float* lat_t1  = lat_x1 + 131072;
    float* latent  = lat_t1 + 131072;
    float* dist    = latent + 131072;     // 2*1984 (pad 4096)
    float* embed   = dist + 4096;         // 2*32*1024
    float* tfout   = embed + 65536;
    float* ref_x1  = tfout + 131072;
    float* ref_t1  = ref_x1 + 131072;
    int*   pn      = (int*)(ref_t1 + 131072);  // 2*1024
    int*   ordg    = pn + 2048;                // 2*1024
    int*   offg    = ordg + 2048;              // 2*1025 (pad 2080)
    int*   maxd    = offg + 2080;              // 2

    // K0: edge distances (needed by MST in K1)
    k0_dist<<<62, 1024, 0, stream>>>(fm, dist);
    // K1: MST (blocks 0,1) || big conv1x1 fm->lat_x1 || embed conv
    k1_fused<<<386, 1024, 0, stream>>>(fm, last_fm, lat_w1, emb_w,
                                       lat_x1, embed, dist, pn, maxd, ordg, offg);
    // K2: treefilter (blocks 0-63) || conv3x3a (lat path)
    k2_fused<<<576, 256, 0, stream>>>(lat_x1, lat_w3a, lat_g, lat_b, lat_m, lat_v,
                                      lat_t1, last_fm, embed, pn, ordg, offg,
                                      maxd, tfout);
    // K3: conv3x3b -> latent
    conv3x3_kernel<<<dim3(4, 64, 2), 256, 0, stream>>>(
        lat_t1, lat_w3b, nullptr, nullptr, nullptr, nullptr, lat_x1, latent, 1);
    // K4: conv1x1 on (latent + tfout)
    conv1x1_add_kernel<<<dim3(16, 8, 2), 1024, 0, stream>>>(
        latent, tfout, ref_w1, ref_x1, 64, 64);
    // K5, K6: refine_residual tail
    conv3x3_kernel<<<dim3(4, 64, 2), 256, 0, stream>>>(
        ref_x1, ref_w3a, ref_g, ref_b, ref_m, ref_v, nullptr, ref_t1, 0);
    conv3x3_kernel<<<dim3(4, 64, 2), 256, 0, stream>>>(
        ref_t1, ref_w3b, nullptr, nullptr, nullptr, nullptr, ref_x1, out, 1);
}

// Round 14
// 226.450 us; speedup vs baseline: 4.7519x; 1.0790x over previous
//
#include <hip/hip_runtime.h>
#include <hip/hip_bf16.h>

#define NN 1024   // nodes = 32*32
#define EE 1984   // grid edges

// ---------------- edge index -> endpoints (matches grid_edges) ----------------
__device__ __forceinline__ void edge_uv(int e, int* u, int* v) {
    if (e < 992) {             // horizontal: idx[:, :-1] -> idx[:, 1:]
        int r = e / 31, c = e - r * 31;
        *u = r * 32 + c; *v = *u + 1;
    } else {                   // vertical: idx[:-1, :] -> idx[1:, :]
        *u = e - 992; *v = *u + 32;
    }
}

// ======================= conv 1x1 tile (1024 threads) ========================
__device__ void conv1x1_tile(const float* __restrict__ in,
                             const float* __restrict__ w,
                             float* __restrict__ out, int CIN, int Cout,
                             int b, int co0, int n0, float* red) {
    int tid = threadIdx.x;
    int px = tid & 63, kc = tid >> 6;
    int kcu = __builtin_amdgcn_readfirstlane(kc);   // wave-uniform -> s_loads for w
    int KCH = CIN >> 4;
    size_t ibase = (size_t)b * CIN * NN + n0 + px;
    const float* wr = w + (size_t)co0 * CIN;
    float acc[8] = {0.f,0.f,0.f,0.f,0.f,0.f,0.f,0.f};
    for (int ci = kcu * KCH; ci < kcu * KCH + KCH; ++ci) {
        float xv = in[ibase + (size_t)ci * NN];
#pragma unroll
        for (int j = 0; j < 8; ++j)
            acc[j] += wr[j * CIN + ci] * xv;
    }
#pragma unroll
    for (int j = 0; j < 8; ++j) red[j * 1024 + tid] = acc[j];
    __syncthreads();
    for (int s = 8; s >= 1; s >>= 1) {
        if (kc < s) {
#pragma unroll
            for (int j = 0; j < 8; ++j)
                red[j * 1024 + kc * 64 + px] += red[j * 1024 + (kc + s) * 64 + px];
        }
        __syncthreads();
    }
    if (kc == 0) {
        size_t ob = ((size_t)b * Cout + co0) * NN + n0 + px;
#pragma unroll
        for (int j = 0; j < 8; ++j) out[ob + (size_t)j * NN] = red[j * 1024 + px];
    }
}

// ============ conv 1x1 64->64, 256 thr, per-pixel (in+in2 fused) =============
// block: 256 px tile, 8 couts. grid: 2b x 8cog x 4 px-tiles = 64 blocks.
__device__ void conv1x1_64(const float* __restrict__ in, const float* __restrict__ in2,
                           const float* __restrict__ w, float* __restrict__ out,
                           int b, int co0, int px0) {
    int tid = threadIdx.x;
    size_t ibase = (size_t)b * 64 * NN + px0 + tid;
    const float* wr = w + (size_t)co0 * 64;
    float acc[8] = {0.f,0.f,0.f,0.f,0.f,0.f,0.f,0.f};
    for (int ci = 0; ci < 64; ++ci) {
        float xv = in[ibase + (size_t)ci * NN] + in2[ibase + (size_t)ci * NN];
#pragma unroll
        for (int j = 0; j < 8; ++j)
            acc[j] += wr[j * 64 + ci] * xv;
    }
    size_t ob = ((size_t)b * 64 + co0) * NN + px0 + tid;
#pragma unroll
    for (int j = 0; j < 8; ++j) out[ob + (size_t)j * NN] = acc[j];
}

// ======================= edge-dist tile (1024 threads) =======================
__device__ void dist_tile(const float* __restrict__ fm, float* __restrict__ dist,
                          int b, int eb, float* red) {
    int tid = threadIdx.x;
    int le = tid & 63, kc = tid >> 6;
    int kcu = __builtin_amdgcn_readfirstlane(kc);
    int e = eb * 64 + le;                  // 31*64 == 1984 exact
    int u, v; edge_uv(e, &u, &v);
    const float* fp = fm + (size_t)b * 1024 * NN;
    float s = 0.f;
    for (int c = kcu * 64; c < kcu * 64 + 64; ++c) {
        float d = fp[(size_t)c * NN + u] - fp[(size_t)c * NN + v];
        s += d * d;
    }
    red[tid] = s;
    __syncthreads();
    for (int ss = 8; ss >= 1; ss >>= 1) {
        if (kc < ss) red[kc * 64 + le] += red[(kc + ss) * 64 + le];
        __syncthreads();
    }
    if (kc == 0) dist[b * EE + e] = red[le];
}

// ===== weight contraction: Wc[co,ci,q] = sum_cm W3a[co,cm,q] * W1[cm,ci] =====
// one block per co (1024 thr, 576 active). conv3x3a(conv1x1(x)) == conv3x3(x,Wc)
// (both linear, no ReLU between -> exact composition up to fp reassociation).
__device__ void wc_contract(const float* __restrict__ w3a, const float* __restrict__ w1,
                            float* __restrict__ wc, int co) {
    int t = threadIdx.x;
    if (t >= 576) return;
    int ci = t / 9, q = t - ci * 9;
    float s = 0.f;
    for (int cm = 0; cm < 64; ++cm)
        s += w3a[((size_t)co * 64 + cm) * 9 + q] * w1[cm * 64 + ci];
    wc[((size_t)co * 64 + ci) * 9 + q] = s;
}

// ========== conv 3x3 body (256 threads, 2-half staging, in+in2 opt) ==========
__device__ void conv3x3_body(const float* __restrict__ in, const float* __restrict__ in2,
                             const float* __restrict__ w,
                             const float* __restrict__ gg, const float* __restrict__ bb,
                             const float* __restrict__ mm, const float* __restrict__ vv,
                             const float* __restrict__ res, float* __restrict__ out,
                             int mode, int b, int co, int r0, float* pl) {
    int tid = threadIdx.x;
    const float* ip = in + (size_t)b * 64 * NN;
    const float* ip2 = in2 ? in2 + (size_t)b * 64 * NN : nullptr;
    const float* wp = w + (size_t)co * 64 * 9;
    int r = tid >> 5, c = tid & 31;
    float acc = 0.f;
    for (int h = 0; h < 2; ++h) {
        __syncthreads();
        for (int i4 = tid; i4 < 32 * 80; i4 += 256) {    // float4 staging
            int ci = i4 / 80, o = i4 - ci * 80;
            int row = r0 - 1 + (o >> 3), c4 = (o & 7) << 2;
            float4 val = make_float4(0.f, 0.f, 0.f, 0.f);
            if (row >= 0 && row < 32) {
                size_t off = (size_t)(h * 32 + ci) * NN + row * 32 + c4;
                val = *(const float4*)&ip[off];
                if (ip2) {
                    float4 v2 = *(const float4*)&ip2[off];
                    val.x += v2.x; val.y += v2.y; val.z += v2.z; val.w += v2.w;
                }
            }
            *(float4*)&pl[ci * 320 + (o >> 3) * 32 + c4] = val;
        }
        __syncthreads();
        for (int ci = 0; ci < 32; ++ci) {
            float wv[9];
#pragma unroll
            for (int q = 0; q < 9; ++q) wv[q] = wp[(h * 32 + ci) * 9 + q];  // uniform
            float s = 0.f;
#pragma unroll
            for (int dy = 0; dy < 3; ++dy) {
                const float* row = &pl[ci * 320 + (r + dy) * 32];
#pragma unroll
                for (int dx = -1; dx <= 1; ++dx) {
                    int cc = c + dx;
                    float xv = (cc >= 0 && cc < 32) ? row[cc] : 0.f;
                    s += wv[dy * 3 + (dx + 1)] * xv;
                }
            }
            acc += s;
        }
    }
    float val;
    size_t op = ((size_t)b * 64 + co) * NN + r0 * 32 + tid;
    if (mode == 0) {
        float sc = gg[co] * rsqrtf(vv[co] + 1e-5f);
        val = acc * sc + (bb[co] - mm[co] * sc);
    } else {
        val = acc + res[op];
    }
    out[op] = fmaxf(val, 0.f);
}

// ============== conv 3x3 (pad 1) full-image body, 1024 threads ===============
// Same accumulation order as conv3x3_body (ci ascending, 9-tap per ci).
__device__ void conv3x3_1024(const float* __restrict__ in, const float* __restrict__ w,
                             const float* __restrict__ gg, const float* __restrict__ bb,
                             const float* __restrict__ mm, const float* __restrict__ vv,
                             const float* __restrict__ res, float* __restrict__ out,
                             int mode, int b, int co, float* pl) {
    int tid = threadIdx.x;
    int r = tid >> 5, c = tid & 31;
    const float* ip = in + (size_t)b * 64 * NN;
    const float* wp = w + (size_t)co * 64 * 9;
    float acc = 0.f;
    for (int h = 0; h < 8; ++h) {
        __syncthreads();
        for (int i4 = tid; i4 < 2048; i4 += 1024) {       // 8 planes x 256 f4
            int ci = i4 >> 8, o4 = (i4 & 255) << 2;
            *(float4*)&pl[ci * 1024 + o4] =
                *(const float4*)&ip[(size_t)(h * 8 + ci) * NN + o4];
        }
        __syncthreads();
        for (int ci = 0; ci < 8; ++ci) {
            float wv[9];
#pragma unroll
            for (int q = 0; q < 9; ++q) wv[q] = wp[(h * 8 + ci) * 9 + q];  // uniform
            const float* P = &pl[ci * 1024];
            float s = 0.f;
#pragma unroll
            for (int dy = -1; dy <= 1; ++dy) {
                int rr = r + dy;
                if (rr < 0 || rr >= 32) continue;
#pragma unroll
                for (int dx = -1; dx <= 1; ++dx) {
                    int cc = c + dx;
                    float xv = (cc >= 0 && cc < 32) ? P[rr * 32 + cc] : 0.f;
                    s += wv[(dy + 1) * 3 + (dx + 1)] * xv;
                }
            }
            acc += s;
        }
    }
    float val;
    size_t op = ((size_t)b * 64 + co) * NN + tid;
    if (mode == 0) {
        float sc = gg[co] * rsqrtf(vv[co] + 1e-5f);
        val = acc * sc + (bb[co] - mm[co] * sc);
    } else {
        val = acc + res[op];
    }
    out[op] = fmaxf(val, 0.f);
}

// =================== 1024-thread MST state (LDS, ~57 KB) =====================
struct MstS {
    unsigned long long minkey[NN];   // later reused as off[] ints
    unsigned long long ekey[EE];     // later reused as depth ping-pong buffers
    int parent[NN], pnw[NN], pn[NN], dep[NN], scr[NN], elist[NN];
    int mstm[EE];
    int cnt, cnt2;
};

// ============ MST body: 1024 threads, reference-faithful (R13) ===============
__device__ void mst_body_1024(const float* __restrict__ dist, int b, MstS* S,
                              int* __restrict__ pn_g, int* __restrict__ maxd_g,
                              int* __restrict__ ord_g, int* __restrict__ off_g) {
    int tid = threadIdx.x;
    const float* wb = dist + b * EE;
    S->parent[tid] = tid;
    S->minkey[tid] = ~0ULL;
    for (int e = tid; e < EE; e += 1024) {
        S->mstm[e] = 0;
        S->ekey[e] = ((unsigned long long)__float_as_uint(wb[e]) << 32) | (unsigned)e;
    }
    if (tid == 0) { S->cnt = 0; S->cnt2 = 0; }
    __syncthreads();

    int r = tid >> 5, c = tid & 31;
    int* P = S->parent;                    // current labels
    int* Q = S->pnw;                       // next labels
    for (int round = 0; round < 14; ++round) {
        int pv = P[tid];
        unsigned long long mk = ~0ULL;
        if (c < 31 && P[tid + 1] != pv) {
            unsigned long long k = S->ekey[r * 31 + c]; if (k < mk) mk = k;
        }
        if (c > 0 && P[tid - 1] != pv) {
            unsigned long long k = S->ekey[r * 31 + c - 1]; if (k < mk) mk = k;
        }
        if (r < 31 && P[tid + 32] != pv) {
            unsigned long long k = S->ekey[992 + r * 32 + c]; if (k < mk) mk = k;
        }
        if (r > 0 && P[tid - 32] != pv) {
            unsigned long long k = S->ekey[992 + (r - 1) * 32 + c]; if (k < mk) mk = k;
        }
        if (mk != ~0ULL) atomicMin(&S->minkey[pv], mk);
        __syncthreads();                   // barrier 1

        unsigned long long sel = S->minkey[tid];
        int np;
        if (sel != ~0ULL) {
            int e = (int)(sel & 0xffffffffULL);
            if (atomicExch(&S->mstm[e], 1) == 0) atomicAdd(&S->cnt, 1);
            int eu, ev; edge_uv(e, &eu, &ev);
            int cu = P[eu], cv = P[ev];
            np = (cu == tid) ? cv : cu;
        } else np = tid;                  // reference: re-singleton when !valid
        int q = np, pq;
        if (q == tid) pq = tid;
        else {
            unsigned long long selq = S->minkey[q];
            if (selq != ~0ULL) {
                int e2 = (int)(selq & 0xffffffffULL);
                int eu2, ev2; edge_uv(e2, &eu2, &ev2);
                int cu2 = P[eu2], cv2 = P[ev2];
                pq = (cu2 == q) ? cv2 : cu2;
            } else pq = q;
        }
        Q[tid] = (pq == tid && tid < q) ? tid : q;   // 2-cycle break
        __syncthreads();                   // barrier 2

        bool first = true;
        for (;;) {                         // 3-jump adaptive flatten (+reset)
            if (first) { S->minkey[tid] = ~0ULL; first = false; }
            int p = Q[tid];
            p = Q[p]; p = Q[p]; p = Q[p];
            Q[tid] = p;
            int ch = (Q[p] != p);
            if (!__syncthreads_or(ch)) break;
        }
        if (S->cnt == NN - 1) break;       // mask complete => final (cut property)
        int* t = P; P = Q; Q = t;
    }

    for (int e = tid; e < EE; e += 1024)
        if (S->mstm[e]) { int s = atomicAdd(&S->cnt2, 1); S->elist[s] = e; }
    __syncthreads();
    int ecnt = S->cnt2;

    // BFS from node 0: 24 unsynced volatile scans per barrier epoch
    S->pn[tid] = (tid == 0) ? 0 : -1;
    __syncthreads();
    volatile int* vpn = S->pn;
    int myu = 0, myv = 0; bool have = tid < ecnt;
    if (have) { edge_uv(S->elist[tid], &myu, &myv); }
    for (;;) {
        int ch = 0;
        for (int s = 0; s < 24; ++s) {
            if (have) {
                int pu = vpn[myu], pv = vpn[myv];
                if (pu >= 0 && pv < 0)      { vpn[myv] = myu; ch = 1; }
                else if (pv >= 0 && pu < 0) { vpn[myu] = myv; ch = 1; }
            }
        }
        if (!__syncthreads_or(ch)) break;
    }
    int incomplete = __syncthreads_or(S->pn[tid] < 0);

    // depth: pointer doubling, -1 wraps to N-1; UNCONDITIONAL barrier each iter.
    S->dep[tid] = (tid != 0) ? 1 : 0;
    S->pnw[tid] = S->pn[tid];
    __syncthreads();
    int* dA = S->dep;  int* dB = (int*)S->ekey;
    int* pA = S->pnw;  int* pB = ((int*)S->ekey) + NN;
    for (int it = 0; it < 12; ++it) {
        int p = pA[tid];
        int j = (p < 0) ? (NN + p) : p;
        dB[tid] = dA[tid] + dA[j];
        int nx = pA[j];
        pB[tid] = nx;
        int anynz = __syncthreads_or(nx != 0);   // barrier ALWAYS executes
        int* t = dA; dA = dB; dB = t;
        t = pA; pA = pB; pB = t;
        if (!incomplete && !anynz) break;
    }
    if (tid == 0) S->cnt = 0;
    __syncthreads();
    int d = dA[tid];
    if (d >= 1 && d <= NN - 1) atomicMax(&S->cnt, d);
    __syncthreads();
    int maxd = S->cnt;

    // counting sort by depth (bucket 0 = root + out-of-range)
    S->scr[tid] = 0;
    __syncthreads();
    int bkt = (tid != 0 && d >= 1 && d <= NN - 1) ? d : 0;
    atomicAdd(&S->scr[bkt], 1);
    __syncthreads();
    int cntv = S->scr[tid];
    int lane = tid & 63, wid = tid >> 6;
    int x = cntv;
    for (int d2 = 1; d2 < 64; d2 <<= 1) {
        int y = __shfl_up(x, d2, 64);
        if (lane >= d2) x += y;
    }
    if (lane == 63) S->pnw[wid] = x;       // wave totals
    __syncthreads();
    if (tid < 16) {
        int off = 0;
        for (int i = 0; i < tid; ++i) off += S->pnw[i];
        S->parent[tid] = off;
    }
    __syncthreads();
    int excl = x - cntv + S->parent[wid];
    int* mi = (int*)S->minkey;             // minkey free now
    mi[tid] = excl;
    S->scr[tid] = excl;                    // running counters
    __syncthreads();
    int pos = atomicAdd(&S->scr[bkt], 1);
    S->elist[pos] = tid;                   // elist reused as ord
    __syncthreads();

    pn_g[b * NN + tid]    = S->pn[tid];
    ord_g[b * NN + tid]   = S->elist[tid];
    off_g[b * 1025 + tid] = mi[tid];
    if (tid == 0) { off_g[b * 1025 + 1024] = NN; maxd_g[b] = maxd; }
}

// =============== tree filter body: ONE WAVE, level-list driven ===============
struct TfSmem { float agg[NN * 3]; float wv[NN]; int jj[NN]; int ords[NN]; int offs[1025]; };
__device__ void treefilter_wave(const float* __restrict__ feat, const float* __restrict__ emb,
                                const int* __restrict__ pn_g, const int* __restrict__ ord_g,
                                const int* __restrict__ off_g, const int* __restrict__ maxd_g,
                                float* __restrict__ tfout, int b, int g, int sub, TfSmem* S) {
    int lane = threadIdx.x;
    const float* eb = emb + ((size_t)b * 32 + g * 8) * NN;
    int c0 = g * 16 + sub * 2;
    const float* fb = feat + ((size_t)b * 64 + c0) * NN;
    for (int k = 0; k < 16; ++k) {
        int v = lane + k * 64;
        int p = pn_g[b * NN + v];
        int j = (p < 0) ? (NN + p) : p;        // JAX negative indexing
        S->jj[v] = j;
        float s = 0.f;
#pragma unroll
        for (int q = 0; q < 8; ++q) {
            float d = eb[(size_t)q * NN + v] - eb[(size_t)q * NN + j];
            s += d * d;
        }
        S->wv[v] = expf(-s);
        S->agg[v * 3 + 0] = fb[v];
        S->agg[v * 3 + 1] = fb[NN + v];
        S->agg[v * 3 + 2] = 1.f;
        S->ords[v] = ord_g[b * NN + v];
        S->offs[v] = off_g[b * 1025 + v];
    }
    if (lane == 0) S->offs[1024] = NN;
    int maxdep = maxd_g[b];
    for (int lev = maxdep; lev >= 1; --lev) {             // up sweep
        int s0 = S->offs[lev], s1 = S->offs[lev + 1];
        for (int i = s0 + lane; i < s1; i += 64) {
            int v = S->ords[i]; int j = S->jj[v]; float w = S->wv[v];
            atomicAdd(&S->agg[j * 3 + 0], w * S->agg[v * 3 + 0]);
            atomicAdd(&S->agg[j * 3 + 1], w * S->agg[v * 3 + 1]);
            atomicAdd(&S->agg[j * 3 + 2], w * S->agg[v * 3 + 2]);
        }
    }
    for (int lev = 1; lev <= maxdep; ++lev) {             // down sweep (in place)
        int s0 = S->offs[lev], s1 = S->offs[lev + 1];
        for (int i = s0 + lane; i < s1; i += 64) {
            int v = S->ords[i]; int j = S->jj[v]; float w = S->wv[v];
#pragma unroll
            for (int c = 0; c < 3; ++c) {
                float a = S->agg[v * 3 + c];
                S->agg[v * 3 + c] = a + w * (S->agg[j * 3 + c] - w * a);
            }
        }
    }
    float* ob = tfout + ((size_t)b * 64 + c0) * NN;
    for (int k = 0; k < 16; ++k) {
        int v = lane + k * 64;
        float inv = 1.f / S->agg[v * 3 + 2];
        ob[v]      = S->agg[v * 3 + 0] * inv;
        ob[NN + v] = S->agg[v * 3 + 1] * inv;
    }
}

// ===== K0: dist (62) + big conv1x1 (256) + Wc contraction (64) @1024 =========
__global__ __launch_bounds__(1024) void k0_fused(
    const float* __restrict__ fm, const float* __restrict__ lat_w1,
    const float* __restrict__ ref_w3a, const float* __restrict__ ref_w1,
    float* __restrict__ lat_x1, float* __restrict__ dist, float* __restrict__ wc) {
    __shared__ __align__(16) float red[8192];
    int bx = blockIdx.x;
    if (bx < 62) {
        dist_tile(fm, dist, bx / 31, bx % 31, red);
    } else if (bx < 318) {
        int i = bx - 62, b = i >> 7, r = i & 127;
        conv1x1_tile(fm, lat_w1, lat_x1, 1024, 64,
                     b, (r >> 4) * 8, (r & 15) * 64, red);
    } else {
        wc_contract(ref_w3a, ref_w1, wc, bx - 318);
    }
}

// ======= K1: MST (0,1) || lat conv3x3a (128) || embed conv (128) @1024 =======
union K1S { float red[8192]; float pl[8192]; MstS m; };
__global__ __launch_bounds__(1024) void k1_fused(
    const float* __restrict__ dist, int* __restrict__ pn_g,
    int* __restrict__ maxd_g, int* __restrict__ ord_g, int* __restrict__ off_g,
    const float* __restrict__ lat_x1, const float* __restrict__ lat_w3a,
    const float* __restrict__ lat_g, const float* __restrict__ lat_b,
    const float* __restrict__ lat_m, const float* __restrict__ lat_v,
    float* __restrict__ lat_t1,
    const float* __restrict__ last_fm, const float* __restrict__ emb_w,
    float* __restrict__ embed) {
    __shared__ __align__(16) K1S s;
    int bx = blockIdx.x;
    if (bx < 2) {
        mst_body_1024(dist, bx, &s.m, pn_g, maxd_g, ord_g, off_g);
    } else if (bx < 130) {
        int t = bx - 2;                    // 128 tasks: 64 co x 2 b
        conv3x3_1024(lat_x1, lat_w3a, lat_g, lat_b, lat_m, lat_v,
                     nullptr, lat_t1, 0, t >> 6, t & 63, s.pl);
    } else {
        int i = bx - 130, b = i >> 6, r = i & 63;
        conv1x1_tile(last_fm, emb_w, embed, 64, 32,
                     b, (r >> 4) * 8, (r & 15) * 64, s.red);
    }
}

// ========= K2: treefilter (0..63) || lat conv3x3b (512) @256 =================
union K2S { float pl[32 * 320]; TfSmem t; };
__global__ __launch_bounds__(256) void k2_fused(
    const float* __restrict__ last_fm, const float* __restrict__ embed,
    const int* __restrict__ pn_g, const int* __restrict__ ord_g,
    const int* __restrict__ off_g, const int* __restrict__ maxd_g,
    float* __restrict__ tfout,
    const float* __restrict__ lat_t1, const float* __restrict__ lat_w3b,
    const float* __restrict__ lat_x1, float* __restrict__ latent) {
    __shared__ __align__(16) K2S s;
    int bx = blockIdx.x;
    if (bx < 64) {                          // TF first: serial chains start ASAP
        if (threadIdx.x >= 64) return;
        treefilter_wave(last_fm, embed, pn_g, ord_g, off_g, maxd_g, tfout,
                        bx >> 5, (bx >> 3) & 3, bx & 7, &s.t);
    } else {
        int i = bx - 64, b = i >> 8, co = (i >> 2) & 63, r0 = (i & 3) * 8;
        conv3x3_body(lat_t1, nullptr, lat_w3b, nullptr, nullptr, nullptr, nullptr,
                     lat_x1, latent, 1, b, co, r0, s.pl);
    }
}

// ==== K3: composed ref3x3 (Wc) on latent+tfout (512) || ref1x1 (64) @256 =====
__global__ __launch_bounds__(256) void k3_fused(
    const float* __restrict__ latent, const float* __restrict__ tfout,
    const float* __restrict__ wc,
    const float* __restrict__ ref_g, const float* __restrict__ ref_b,
    const float* __restrict__ ref_m, const float* __restrict__ ref_v,
    const float* __restrict__ ref_w1,
    float* __restrict__ ref_t1, float* __restrict__ ref_x1) {
    __shared__ __align__(16) float pl[32 * 320];
    int bx = blockIdx.x;
    if (bx < 512) {                         // t = relu(bn(conv3x3(fusion, Wc)))
        int b = bx >> 8, co = (bx >> 2) & 63, r0 = (bx & 3) * 8;
        conv3x3_body(latent, tfout, wc, ref_g, ref_b, ref_m, ref_v,
                     nullptr, ref_t1, 0, b, co, r0, pl);
    } else {                                // ref_x1 = conv1x1(fusion) (residual)
        int i = bx - 512, b = i >> 5, co0 = ((i >> 2) & 7) * 8, px0 = (i & 3) * 256;
        conv1x1_64(latent, tfout, ref_w1, ref_x1, b, co0, px0);
    }
}

// ================== K4: ref conv3x3b + residual + relu @256 ==================
__global__ __launch_bounds__(256) void k4_tail(
    const float* __restrict__ ref_t1, const float* __restrict__ ref_w3b,
    const float* __restrict__ ref_x1, float* __restrict__ out) {
    __shared__ __align__(16) float pl[32 * 320];
    int bx = blockIdx.x;
    int b = bx >> 8, co = (bx >> 2) & 63, r0 = (bx & 3) * 8;
    conv3x3_body(ref_t1, nullptr, ref_w3b, nullptr, nullptr, nullptr, nullptr,
                 ref_x1, out, 1, b, co, r0, pl);
}

// ----------------------------- host launcher ---------------------------------
extern "C" void kernel_launch(void* const* d_in, const int* in_sizes, int n_in,
                              void* d_out, int out_size, void* d_ws, size_t ws_size,
                              hipStream_t stream) {
    const float* fm      = (const float*)d_in[0];
    const float* last_fm = (const float*)d_in[1];
    const float* lat_w1  = (const float*)d_in[2];
    const float* lat_w3a = (const float*)d_in[3];
    const float* lat_g   = (const float*)d_in[4];
    const float* lat_b   = (const float*)d_in[5];
    const float* lat_m   = (const float*)d_in[6];
    const float* lat_v   = (const float*)d_in[7];
    const float* lat_w3b = (const float*)d_in[8];
    const float* ref_w1  = (const float*)d_in[9];
    const float* ref_w3a = (const float*)d_in[10];
    const float* ref_g   = (const float*)d_in[11];
    const float* ref_b   = (const float*)d_in[12];
    const float* ref_m   = (const float*)d_in[13];
    const float* ref_v   = (const float*)d_in[14];
    const float* ref_w3b = (const float*)d_in[15];
    const float* emb_w   = (const float*)d_in[16];
    float* out = (float*)d_out;

    float* ws      = (float*)d_ws;
    float* lat_x1  = ws;                  // 2*64*1024
    float* lat_t1  = lat_x1 + 131072;
    float* latent  = lat_t1 + 131072;
    float* dist    = latent + 131072;     // 2*1984 (pad 4096)
    float* embed   = dist + 4096;         // 2*32*1024
    float* tfout   = embed + 65536;
    float* ref_x1  = tfout + 131072;
    float* ref_t1  = ref_x1 + 131072;
    float* wc      = ref_t1 + 131072;     // 64*64*9 = 36864 (pad 36992)
    int*   pn      = (int*)(wc + 36992);  // 2*1024
    int*   ordg    = pn + 2048;           // 2*1024
    int*   offg    = ordg + 2048;         // 2*1025 (pad 2080)
    int*   maxd    = offg + 2080;         // 2

    // K0: dist + big conv1x1 fm->lat_x1 + Wc = ref_w3a o ref_w1
    k0_fused<<<382, 1024, 0, stream>>>(fm, lat_w1, ref_w3a, ref_w1,
                                       lat_x1, dist, wc);
    // K1: MST || lat conv3x3a (lat_x1->lat_t1) || embed conv
    k1_fused<<<258, 1024, 0, stream>>>(dist, pn, maxd, ordg, offg,
                                       lat_x1, lat_w3a, lat_g, lat_b, lat_m, lat_v,
                                       lat_t1, last_fm, emb_w, embed);
    // K2: treefilter -> tfout || lat conv3x3b (lat_t1 + lat_x1 -> latent)
    k2_fused<<<576, 256, 0, stream>>>(last_fm, embed, pn, ordg, offg, maxd,
                                      tfout, lat_t1, lat_w3b, lat_x1, latent);
    // K3: composed ref3x3(Wc) on fusion -> ref_t1  ||  ref1x1 on fusion -> ref_x1
    k3_fused<<<576, 256, 0, stream>>>(latent, tfout, wc,
                                      ref_g, ref_b, ref_m, ref_v, ref_w1,
                                      ref_t1, ref_x1);
    // K4: ref conv3x3b + residual + relu -> out
    k4_tail<<<512, 256, 0, stream>>>(ref_t1, ref_w3b, ref_x1, out);
}